// Round 15
// baseline (112.154 us; speedup 1.0000x reference)
//
#include <hip/hip_runtime.h>
#include <math.h>
#include <stdint.h>

// B=2, N=512, D=64, DH=64
#define NN 512
#define RR 1024   // 2*NN rows

typedef float f4 __attribute__((ext_vector_type(4)));
#define AS1 __attribute__((address_space(1)))
#define AS3 __attribute__((address_space(3)))

// ---------------- prep: blocks 0-2 = weight-product precompute; blocks 3-34 = proj3 ----------------
__global__ __launch_bounds__(256) void prep_kernel(
    const float* __restrict__ x,
    const float* __restrict__ Wq1, const float* __restrict__ bq1,
    const float* __restrict__ Wk1, const float* __restrict__ bk1,
    const float* __restrict__ Wv1, const float* __restrict__ bv1,
    const float* __restrict__ Wkn, const float* __restrict__ bkn,
    const float* __restrict__ Wvn, const float* __restrict__ bvn,
    const float* __restrict__ Wqe, const float* __restrict__ bqe,
    const float* __restrict__ Wke, const float* __restrict__ Wve,
    float* __restrict__ Q, float* __restrict__ K, float* __restrict__ V,
    float* __restrict__ M_P, float* __restrict__ c_P,
    float* __restrict__ M_ke, float* __restrict__ c_ke,
    float* __restrict__ M_ve, float* __restrict__ c_ve,
    float* __restrict__ vq0, float* __restrict__ s0p)
{
    __shared__ float sh[14528];
    const int t = threadIdx.x;

    if (blockIdx.x < 3) {
        const int m = blockIdx.x;
        float* As = sh;
        float* Bs = sh + 4160;
        float* va = sh + 8320;
        float* vb = sh + 8384;
        const float* A  = (m == 0) ? Wkn : Wvn;
        const float* aV = (m == 0) ? bkn : bvn;
        const float* B  = (m == 0) ? Wqe : (m == 1 ? Wke : Wve);
#pragma unroll
        for (int p = 0; p < 16; ++p) {
            const int idx = p * 256 + t;
            const int r = idx >> 6, cc = idx & 63;
            As[r * 65 + cc] = A[idx];
            if (m == 0) Bs[r * 65 + cc] = B[idx];
            else        Bs[cc * 65 + r] = B[idx];
        }
        if (t < 64) { va[t] = aV[t]; vb[t] = bqe[t]; }
        __syncthreads();

        const int b = t & 63, g = t >> 6;
        float acc[16];
#pragma unroll
        for (int aa = 0; aa < 16; ++aa) acc[aa] = 0.f;
        for (int k = 0; k < 64; ++k) {
            const float bv = Bs[b * 65 + k];
#pragma unroll
            for (int aa = 0; aa < 16; ++aa)
                acc[aa] = fmaf(As[(g * 16 + aa) * 65 + k], bv, acc[aa]);
        }
        float* M = (m == 0) ? M_P : (m == 1 ? M_ke : M_ve);
#pragma unroll
        for (int aa = 0; aa < 16; ++aa)
            M[(g * 16 + aa) * 64 + b] = acc[aa];

        if (t < 64) {
            float cb = 0.f;
            for (int k = 0; k < 64; ++k) cb = fmaf(va[k], Bs[t * 65 + k], cb);
            float* C = (m == 0) ? c_P : (m == 1 ? c_ke : c_ve);
            C[t] = cb;
            if (m == 0) {
                float q = 0.f;
                for (int k = 0; k < 64; ++k) q = fmaf(As[t * 65 + k], vb[k], q);
                vq0[t] = q * 0.125f;
            }
        }
        if (m == 0 && t == 0) {
            float s = 0.f;
            for (int k = 0; k < 64; ++k) s += vb[k] * va[k];
            *s0p = s * 0.125f;
        }
    } else {
        const int rb = (blockIdx.x - 3) * 32;
        float* Ws0 = sh;
        float* Ws1 = sh + 4096;
        float* Ws2 = sh + 8192;
        float* xs  = sh + 12288;
        float* bs0 = sh + 14336;
        float* bs1 = sh + 14400;
        float* bs2 = sh + 14464;
#pragma unroll
        for (int p = 0; p < 4; ++p) {
            const int idx = p * 256 + t;
            ((f4*)Ws0)[idx] = ((const f4*)Wq1)[idx];
            ((f4*)Ws1)[idx] = ((const f4*)Wk1)[idx];
            ((f4*)Ws2)[idx] = ((const f4*)Wv1)[idx];
        }
        ((f4*)xs)[t]       = ((const f4*)(x + rb * 64))[t];
        ((f4*)xs)[t + 256] = ((const f4*)(x + rb * 64))[t + 256];
        if (t < 64) { bs0[t] = bq1[t]; bs1[t] = bk1[t]; bs2[t] = bv1[t]; }
        __syncthreads();

        const int d = t & 63, g = t >> 6;
        float a0[8], a1[8], a2[8];
#pragma unroll
        for (int r = 0; r < 8; ++r) { a0[r] = bs0[d]; a1[r] = bs1[d]; a2[r] = bs2[d]; }
        for (int k4 = 0; k4 < 16; ++k4) {
            float w0[4], w1[4], w2[4];
#pragma unroll
            for (int kk = 0; kk < 4; ++kk) {
                w0[kk] = Ws0[(k4 * 4 + kk) * 64 + d];
                w1[kk] = Ws1[(k4 * 4 + kk) * 64 + d];
                w2[kk] = Ws2[(k4 * 4 + kk) * 64 + d];
            }
#pragma unroll
            for (int r = 0; r < 8; ++r) {
                const f4 xv = ((const f4*)xs)[(g * 8 + r) * 16 + k4];
                a0[r] = fmaf(xv.x, w0[0], fmaf(xv.y, w0[1], fmaf(xv.z, w0[2], fmaf(xv.w, w0[3], a0[r]))));
                a1[r] = fmaf(xv.x, w1[0], fmaf(xv.y, w1[1], fmaf(xv.z, w1[2], fmaf(xv.w, w1[3], a1[r]))));
                a2[r] = fmaf(xv.x, w2[0], fmaf(xv.y, w2[1], fmaf(xv.z, w2[2], fmaf(xv.w, w2[3], a2[r]))));
            }
        }
#pragma unroll
        for (int r = 0; r < 8; ++r) {
            Q[(rb + g * 8 + r) * 64 + d] = a0[r];
            K[(rb + g * 8 + r) * 64 + d] = a1[r];
            V[(rb + g * 8 + r) * 64 + d] = a2[r];
        }
    }
}

// ---------- node-to-node self attention (512 thr): x_hat = softmax(QK^T/8) @ V ----------
__global__ __launch_bounds__(512) void selfattn_kernel(
    const float* __restrict__ Q, const float* __restrict__ K,
    const float* __restrict__ V, float* __restrict__ xhat)
{
    const int row = blockIdx.x;            // b*512 + n
    const int b = row >> 9;
    const int t = threadIdx.x;
    __shared__ float qr[64];
    __shared__ float p[512];
    __shared__ float red[512];
    if (t < 64) qr[t] = Q[row * 64 + t];
    __syncthreads();

    {
        const int m = t;
        const f4* kr = (const f4*)(K + (size_t)(b * NN + m) * 64);
        const f4* qq = (const f4*)qr;
        float sp[4] = {0.f, 0.f, 0.f, 0.f};
#pragma unroll
        for (int u = 0; u < 16; ++u) {
            const f4 w = kr[u];
            const f4 qv = qq[u];
            sp[u & 3] += qv.x * w.x + qv.y * w.y + qv.z * w.z + qv.w * w.w;
        }
        p[m] = ((sp[0] + sp[1]) + (sp[2] + sp[3])) * 0.125f;
    }
    __syncthreads();

    const int lane = t & 63, w = t >> 6;
    const float v0 = p[t];
    float m = v0;
#pragma unroll
    for (int o = 1; o < 64; o <<= 1) m = fmaxf(m, __shfl_xor(m, o));
    if (lane == 0) red[w] = m;
    __syncthreads();
    float mx = red[0];
#pragma unroll
    for (int z = 1; z < 8; ++z) mx = fmaxf(mx, red[z]);
    const float e0 = expf(v0 - mx);
    float ss = e0;
#pragma unroll
    for (int o = 1; o < 64; o <<= 1) ss += __shfl_xor(ss, o);
    if (lane == 0) red[8 + w] = ss;
    __syncthreads();
    const float inv = 1.f / (red[8] + red[9] + red[10] + red[11]
                           + red[12] + red[13] + red[14] + red[15]);
    p[t] = e0;
    __syncthreads();

    const int d = t & 63, q = t >> 6;
    float acc = 0.f;
    const int j0 = q * 64;
    for (int j = j0; j < j0 + 64; ++j)
        acc = fmaf(p[j], V[(b * NN + j) * 64 + d], acc);
    red[t] = acc;
    __syncthreads();
    if (t < 64) {
        float s8 = 0.f;
#pragma unroll
        for (int z = 0; z < 8; ++z) s8 += red[t + z * 64];
        xhat[row * 64 + t] = s8 * inv;
    }
}

// ---------------- fused affine maps of xhat: Qn, Vn, P, VnWke, VnWve, q0 ----------------
__global__ __launch_bounds__(256) void affine5_kernel(
    const float* __restrict__ xhat,
    const float* __restrict__ Wqn, const float* __restrict__ bqn,
    const float* __restrict__ Wvn, const float* __restrict__ bvn,
    const float* __restrict__ M_P, const float* __restrict__ c_P,
    const float* __restrict__ M_ke, const float* __restrict__ c_ke,
    const float* __restrict__ M_ve, const float* __restrict__ c_ve,
    const float* __restrict__ vq0, const float* __restrict__ s0p,
    float* __restrict__ Qn, float* __restrict__ Vn, float* __restrict__ P,
    float* __restrict__ VnWke, float* __restrict__ VnWve, float* __restrict__ q0)
{
    const int t = threadIdx.x;
    const int rb = blockIdx.x * 32;
    const int m = blockIdx.y;
    const float* W; const float* c; float* o;
    if (m == 0)      { W = Wqn;  c = bqn;  o = Qn; }
    else if (m == 1) { W = Wvn;  c = bvn;  o = Vn; }
    else if (m == 2) { W = M_P;  c = c_P;  o = P; }
    else if (m == 3) { W = M_ke; c = c_ke; o = VnWke; }
    else             { W = M_ve; c = c_ve; o = VnWve; }
    __shared__ float Ws[4096], xs[2048], cs[64], vq0s[64];
#pragma unroll
    for (int p = 0; p < 4; ++p) ((f4*)Ws)[p * 256 + t] = ((const f4*)W)[p * 256 + t];
    ((f4*)xs)[t]       = ((const f4*)(xhat + rb * 64))[t];
    ((f4*)xs)[t + 256] = ((const f4*)(xhat + rb * 64))[t + 256];
    if (t < 64) { cs[t] = c[t]; if (m == 0) vq0s[t] = vq0[t]; }
    __syncthreads();

    const int d = t & 63, g = t >> 6;
    float acc[8];
#pragma unroll
    for (int r = 0; r < 8; ++r) acc[r] = cs[d];
    for (int k4 = 0; k4 < 16; ++k4) {
        float w[4];
#pragma unroll
        for (int kk = 0; kk < 4; ++kk) w[kk] = Ws[(k4 * 4 + kk) * 64 + d];
#pragma unroll
        for (int r = 0; r < 8; ++r) {
            const f4 xv = ((const f4*)xs)[(g * 8 + r) * 16 + k4];
            acc[r] = fmaf(xv.x, w[0], fmaf(xv.y, w[1], fmaf(xv.z, w[2], fmaf(xv.w, w[3], acc[r]))));
        }
    }
#pragma unroll
    for (int r = 0; r < 8; ++r) o[(rb + g * 8 + r) * 64 + d] = acc[r];

    if (m == 0) {
        const int row = t >> 3, seg = t & 7;
        float part = 0.f;
#pragma unroll
        for (int kk = 0; kk < 8; ++kk)
            part = fmaf(xs[row * 64 + seg * 8 + kk], vq0s[seg * 8 + kk], part);
        part += __shfl_xor(part, 1);
        part += __shfl_xor(part, 2);
        part += __shfl_xor(part, 4);
        if (seg == 0) q0[rb + row] = part + s0p[0];
    }
}

// ---------- streaming edge pass: async LDS staging + online reductions, CACHED stores ----------
__global__ __launch_bounds__(256, 8) void edge_kernel(
    const float* __restrict__ e, const float* __restrict__ P,
    const float* __restrict__ q0, const float* __restrict__ Vn,
    const float* __restrict__ Qn, const float* __restrict__ VnWke,
    const float* __restrict__ VnWve,
    float* __restrict__ e_new,
    float* __restrict__ Epart, float* __restrict__ Gpart, float* __restrict__ Wpart)
{
    const int blk = blockIdx.x;
    const int bi = blk >> 3;         // b*512 + i
    const int jc = blk & 7;          // 64-j chunk
    const int b  = bi >> 9;
    const int t  = threadIdx.x;
    const int r  = t >> 4;           // row slot 0..15
    const int k  = t & 15;           // float4 lane
    const int w  = t >> 6;           // wave
    const int l  = t & 63;           // lane

    __shared__ float esh[4104];      // 16KB e-chunk; tail reused for Wred/EG

    // ---- async stage: 16 segments of 1KB; wave w stages segments w,4+w,8+w,12+w ----
    const float* ebase = e + (size_t)bi * NN * 64 + (size_t)jc * 64 * 64;
#pragma unroll
    for (int it = 0; it < 4; ++it) {
        const int seg = it * 4 + w;
        const char* gsrc = (const char*)ebase + seg * 1024 + l * 16;
        float* ldst = esh + seg * 256;        // wave-uniform base; HW adds lane*16
        __builtin_amdgcn_global_load_lds((const AS1 void*)gsrc, (AS3 void*)ldst,
                                         16, 0, 0);
    }

    // ---- independent prolog while loads fly ----
    const float q0i = q0[bi];
    const f4 pi4 = ((const f4*)P)[bi * 16 + k];
    const f4 vi4 = ((const f4*)Vn)[bi * 16 + k];
    const f4 qn4 = ((const f4*)Qn)[bi * 16 + k];
    const f4 wi4 = ((const f4*)VnWke)[bi * 16 + k];
    float uii = qn4.x * wi4.x + qn4.y * wi4.y + qn4.z * wi4.z + qn4.w * wi4.w;
    uii += __shfl_xor(uii, 1);
    uii += __shfl_xor(uii, 2);
    uii += __shfl_xor(uii, 4);
    uii += __shfl_xor(uii, 8);
    uii *= 0.125f;

    const f4* Prow  = (const f4*)P     + (size_t)b * NN * 16;
    const f4* Vrow  = (const f4*)Vn    + (size_t)b * NN * 16;
    const f4* Krow  = (const f4*)VnWke + (size_t)b * NN * 16;
    const f4* Wvrow = (const f4*)VnWve + (size_t)b * NN * 16;
    const float* q0b = q0 + b * NN;
    f4* enrow = (f4*)(e_new + (size_t)bi * NN * 64);

    __syncthreads();   // drains vmcnt -> e chunk resident in LDS

    float Eacc = 0.f, Gacc = 0.f;
    f4 Wacc = {0.f, 0.f, 0.f, 0.f};

#pragma unroll
    for (int it = 0; it < 4; ++it) {
        const int jl = it * 16 + r;          // local row
        const int j  = jc * 64 + jl;         // row in batch
        const f4 ev = ((const f4*)esh)[jl * 16 + k];
        const f4 pj = Prow[j * 16 + k];
        const f4 wj = Krow[j * 16 + k];
        const f4 vj = Vrow[j * 16 + k];
        const f4 wv = Wvrow[j * 16 + k];
        float s = ev.x * (pj.x - pi4.x) + ev.y * (pj.y - pi4.y)
                + ev.z * (pj.z - pi4.z) + ev.w * (pj.w - pi4.w);
        float uu = qn4.x * wj.x + qn4.y * wj.y + qn4.z * wj.z + qn4.w * wj.w;
        s  += __shfl_xor(s, 1);  uu += __shfl_xor(uu, 1);
        s  += __shfl_xor(s, 2);  uu += __shfl_xor(uu, 2);
        s  += __shfl_xor(s, 4);  uu += __shfl_xor(uu, 4);
        s  += __shfl_xor(s, 8);  uu += __shfl_xor(uu, 8);
        const float ai = 1.f / (1.f + expf(-(s * 0.125f + q0b[j] - q0i)));
        f4 en;
        en.x = fmaf(ai, vj.x - vi4.x, vi4.x);
        en.y = fmaf(ai, vj.y - vi4.y, vi4.y);
        en.z = fmaf(ai, vj.z - vi4.z, vi4.z);
        en.w = fmaf(ai, vj.w - vi4.w, vi4.w);
        enrow[j * 16 + k] = en;              // CACHED store (A/B vs NT)
        const float ex  = expf(ai * (uu * 0.125f - uii));
        const float aex = ai * ex;
        Eacc += ex;
        Gacc += aex;
        Wacc.x = fmaf(aex, wv.x, Wacc.x);
        Wacc.y = fmaf(aex, wv.y, Wacc.y);
        Wacc.z = fmaf(aex, wv.z, Wacc.z);
        Wacc.w = fmaf(aex, wv.w, Wacc.w);
    }

    // cross-row reduce within wave (rows at lanes l^16 / l^32)
    Eacc += __shfl_xor(Eacc, 16);  Eacc += __shfl_xor(Eacc, 32);
    Gacc += __shfl_xor(Gacc, 16);  Gacc += __shfl_xor(Gacc, 32);
    Wacc.x += __shfl_xor(Wacc.x, 16);  Wacc.x += __shfl_xor(Wacc.x, 32);
    Wacc.y += __shfl_xor(Wacc.y, 16);  Wacc.y += __shfl_xor(Wacc.y, 32);
    Wacc.z += __shfl_xor(Wacc.z, 16);  Wacc.z += __shfl_xor(Wacc.z, 32);
    Wacc.w += __shfl_xor(Wacc.w, 16);  Wacc.w += __shfl_xor(Wacc.w, 32);

    __syncthreads();   // all esh reads done; safe to alias reduction buffers
    float* Wred = esh;               // [4][65]
    float* EG   = esh + 4 * 65;      // [8]
    if (l < 16) {
        Wred[w * 65 + l * 4 + 0] = Wacc.x;
        Wred[w * 65 + l * 4 + 1] = Wacc.y;
        Wred[w * 65 + l * 4 + 2] = Wacc.z;
        Wred[w * 65 + l * 4 + 3] = Wacc.w;
        if (l == 0) { EG[w] = Eacc; EG[4 + w] = Gacc; }
    }
    __syncthreads();
    if (t < 64) {
        const float Wsum = Wred[0 * 65 + t] + Wred[1 * 65 + t]
                         + Wred[2 * 65 + t] + Wred[3 * 65 + t];
        Wpart[((size_t)jc * RR + bi) * 64 + t] = Wsum;
        if (t == 0) {
            Epart[jc * RR + bi] = EG[0] + EG[1] + EG[2] + EG[3];
            Gpart[jc * RR + bi] = EG[4] + EG[5] + EG[6] + EG[7];
        }
    }
}

// ---------- final: combine 8 partials per row -> x_new ----------
__global__ __launch_bounds__(64) void final_kernel(
    const float* __restrict__ Epart, const float* __restrict__ Gpart,
    const float* __restrict__ Wpart, const float* __restrict__ VnWve,
    const float* __restrict__ bve, float* __restrict__ x_new)
{
    const int bi = blockIdx.x;
    const int t = threadIdx.x;
    float Wsum = 0.f;
#pragma unroll
    for (int jc = 0; jc < 8; ++jc)
        Wsum += Wpart[((size_t)jc * RR + bi) * 64 + t];
    float E = 0.f, G = 0.f;
#pragma unroll
    for (int jc = 0; jc < 8; ++jc) {
        E += Epart[jc * RR + bi];
        G += Gpart[jc * RR + bi];
    }
    const float inv = 1.f / E;
    x_new[(size_t)bi * 64 + t] = bve[t] + VnWve[(size_t)bi * 64 + t] * (1.f - G * inv)
                               + Wsum * inv;
}

extern "C" void kernel_launch(void* const* d_in, const int* in_sizes, int n_in,
                              void* d_out, int out_size, void* d_ws, size_t ws_size,
                              hipStream_t stream) {
    const float* x   = (const float*)d_in[0];
    const float* e   = (const float*)d_in[1];
    const float* Wq1 = (const float*)d_in[2];  const float* bq1 = (const float*)d_in[3];
    const float* Wk1 = (const float*)d_in[4];  const float* bk1 = (const float*)d_in[5];
    const float* Wv1 = (const float*)d_in[6];  const float* bv1 = (const float*)d_in[7];
    const float* Wqe = (const float*)d_in[8];  const float* bqe = (const float*)d_in[9];
    const float* Wkn = (const float*)d_in[10]; const float* bkn = (const float*)d_in[11];
    const float* Wvn = (const float*)d_in[12]; const float* bvn = (const float*)d_in[13];
    const float* Wqn = (const float*)d_in[14]; const float* bqn = (const float*)d_in[15];
    const float* Wke = (const float*)d_in[16]; /* bke cancels in softmax */
    const float* Wve = (const float*)d_in[18]; const float* bve = (const float*)d_in[19];

    float* out = (float*)d_out;
    float* x_new = out;                 // (2,512,64)
    float* e_new = out + 2 * NN * 64;   // (2,512,512,64)

    float* ws = (float*)d_ws;
    float* Q     = ws;                  // RR*64 each
    float* K     = Q + RR * 64;
    float* V     = K + RR * 64;
    float* xhat  = V + RR * 64;
    float* Qn    = xhat + RR * 64;
    float* Vn    = Qn + RR * 64;
    float* P     = Vn + RR * 64;
    float* VnWke = P + RR * 64;
    float* VnWve = VnWke + RR * 64;
    float* q0    = VnWve + RR * 64;     // RR
    float* M_P   = q0 + RR;             // 4096 each
    float* M_ke  = M_P + 4096;
    float* M_ve  = M_ke + 4096;
    float* c_P   = M_ve + 4096;         // 64 each
    float* c_ke  = c_P + 64;
    float* c_ve  = c_ke + 64;
    float* vq0   = c_ve + 64;
    float* s0    = vq0 + 64;            // 64 (pad)
    float* Epart = s0 + 64;             // 8*RR
    float* Gpart = Epart + 8 * RR;      // 8*RR
    float* Wpart = Gpart + 8 * RR;      // 8*RR*64

    prep_kernel<<<35, 256, 0, stream>>>(x, Wq1, bq1, Wk1, bk1, Wv1, bv1,
                                        Wkn, bkn, Wvn, bvn, Wqe, bqe, Wke, Wve,
                                        Q, K, V,
                                        M_P, c_P, M_ke, c_ke, M_ve, c_ve, vq0, s0);
    selfattn_kernel<<<RR, 512, 0, stream>>>(Q, K, V, xhat);
    affine5_kernel<<<dim3(32, 5), 256, 0, stream>>>(xhat, Wqn, bqn, Wvn, bvn,
                                                    M_P, c_P, M_ke, c_ke, M_ve, c_ve,
                                                    vq0, s0,
                                                    Qn, Vn, P, VnWke, VnWve, q0);
    edge_kernel<<<RR * 8, 256, 0, stream>>>(e, P, q0, Vn, Qn, VnWke, VnWve,
                                            e_new, Epart, Gpart, Wpart);
    final_kernel<<<RR, 64, 0, stream>>>(Epart, Gpart, Wpart, VnWve, bve, x_new);
}

// Round 16
// 82.529 us; speedup vs baseline: 1.3590x; 1.3590x over previous
//
#include <hip/hip_runtime.h>
#include <math.h>

// B=2, N=512, D=64, DH=64
#define NN 512
#define RR 1024   // 2*NN rows

typedef float f4 __attribute__((ext_vector_type(4)));

// ---------------- prep: blocks 0-2 = weight-product precompute; blocks 3-34 = proj3 ----------------
__global__ __launch_bounds__(256) void prep_kernel(
    const float* __restrict__ x,
    const float* __restrict__ Wq1, const float* __restrict__ bq1,
    const float* __restrict__ Wk1, const float* __restrict__ bk1,
    const float* __restrict__ Wv1, const float* __restrict__ bv1,
    const float* __restrict__ Wkn, const float* __restrict__ bkn,
    const float* __restrict__ Wvn, const float* __restrict__ bvn,
    const float* __restrict__ Wqe, const float* __restrict__ bqe,
    const float* __restrict__ Wke, const float* __restrict__ Wve,
    float* __restrict__ Q, float* __restrict__ K, float* __restrict__ V,
    float* __restrict__ M_P, float* __restrict__ c_P,
    float* __restrict__ M_ke, float* __restrict__ c_ke,
    float* __restrict__ M_ve, float* __restrict__ c_ve,
    float* __restrict__ vq0, float* __restrict__ s0p)
{
    __shared__ float sh[14528];
    const int t = threadIdx.x;

    if (blockIdx.x < 3) {
        const int m = blockIdx.x;
        float* As = sh;
        float* Bs = sh + 4160;
        float* va = sh + 8320;
        float* vb = sh + 8384;
        const float* A  = (m == 0) ? Wkn : Wvn;
        const float* aV = (m == 0) ? bkn : bvn;
        const float* B  = (m == 0) ? Wqe : (m == 1 ? Wke : Wve);
#pragma unroll
        for (int p = 0; p < 16; ++p) {
            const int idx = p * 256 + t;
            const int r = idx >> 6, cc = idx & 63;
            As[r * 65 + cc] = A[idx];
            if (m == 0) Bs[r * 65 + cc] = B[idx];
            else        Bs[cc * 65 + r] = B[idx];
        }
        if (t < 64) { va[t] = aV[t]; vb[t] = bqe[t]; }
        __syncthreads();

        const int b = t & 63, g = t >> 6;
        float acc[16];
#pragma unroll
        for (int aa = 0; aa < 16; ++aa) acc[aa] = 0.f;
        for (int k = 0; k < 64; ++k) {
            const float bv = Bs[b * 65 + k];
#pragma unroll
            for (int aa = 0; aa < 16; ++aa)
                acc[aa] = fmaf(As[(g * 16 + aa) * 65 + k], bv, acc[aa]);
        }
        float* M = (m == 0) ? M_P : (m == 1 ? M_ke : M_ve);
#pragma unroll
        for (int aa = 0; aa < 16; ++aa)
            M[(g * 16 + aa) * 64 + b] = acc[aa];

        if (t < 64) {
            float cb = 0.f;
            for (int k = 0; k < 64; ++k) cb = fmaf(va[k], Bs[t * 65 + k], cb);
            float* C = (m == 0) ? c_P : (m == 1 ? c_ke : c_ve);
            C[t] = cb;
            if (m == 0) {
                float q = 0.f;
                for (int k = 0; k < 64; ++k) q = fmaf(As[t * 65 + k], vb[k], q);
                vq0[t] = q * 0.125f;
            }
        }
        if (m == 0 && t == 0) {
            float s = 0.f;
            for (int k = 0; k < 64; ++k) s += vb[k] * va[k];
            *s0p = s * 0.125f;
        }
    } else {
        const int rb = (blockIdx.x - 3) * 32;
        float* Ws0 = sh;
        float* Ws1 = sh + 4096;
        float* Ws2 = sh + 8192;
        float* xs  = sh + 12288;
        float* bs0 = sh + 14336;
        float* bs1 = sh + 14400;
        float* bs2 = sh + 14464;
#pragma unroll
        for (int p = 0; p < 4; ++p) {
            const int idx = p * 256 + t;
            ((f4*)Ws0)[idx] = ((const f4*)Wq1)[idx];
            ((f4*)Ws1)[idx] = ((const f4*)Wk1)[idx];
            ((f4*)Ws2)[idx] = ((const f4*)Wv1)[idx];
        }
        ((f4*)xs)[t]       = ((const f4*)(x + rb * 64))[t];
        ((f4*)xs)[t + 256] = ((const f4*)(x + rb * 64))[t + 256];
        if (t < 64) { bs0[t] = bq1[t]; bs1[t] = bk1[t]; bs2[t] = bv1[t]; }
        __syncthreads();

        const int d = t & 63, g = t >> 6;
        float a0[8], a1[8], a2[8];
#pragma unroll
        for (int r = 0; r < 8; ++r) { a0[r] = bs0[d]; a1[r] = bs1[d]; a2[r] = bs2[d]; }
        for (int k4 = 0; k4 < 16; ++k4) {
            float w0[4], w1[4], w2[4];
#pragma unroll
            for (int kk = 0; kk < 4; ++kk) {
                w0[kk] = Ws0[(k4 * 4 + kk) * 64 + d];
                w1[kk] = Ws1[(k4 * 4 + kk) * 64 + d];
                w2[kk] = Ws2[(k4 * 4 + kk) * 64 + d];
            }
#pragma unroll
            for (int r = 0; r < 8; ++r) {
                const f4 xv = ((const f4*)xs)[(g * 8 + r) * 16 + k4];
                a0[r] = fmaf(xv.x, w0[0], fmaf(xv.y, w0[1], fmaf(xv.z, w0[2], fmaf(xv.w, w0[3], a0[r]))));
                a1[r] = fmaf(xv.x, w1[0], fmaf(xv.y, w1[1], fmaf(xv.z, w1[2], fmaf(xv.w, w1[3], a1[r]))));
                a2[r] = fmaf(xv.x, w2[0], fmaf(xv.y, w2[1], fmaf(xv.z, w2[2], fmaf(xv.w, w2[3], a2[r]))));
            }
        }
#pragma unroll
        for (int r = 0; r < 8; ++r) {
            Q[(rb + g * 8 + r) * 64 + d] = a0[r];
            K[(rb + g * 8 + r) * 64 + d] = a1[r];
            V[(rb + g * 8 + r) * 64 + d] = a2[r];
        }
    }
}

// ---------- self attention, 4 rows/block (256 thr): K/V read amortized 4x, wave-local softmax ----------
__global__ __launch_bounds__(256) void selfattn4_kernel(
    const float* __restrict__ Q, const float* __restrict__ K,
    const float* __restrict__ V, float* __restrict__ xhat)
{
    const int rb = blockIdx.x * 4;         // first of 4 rows (never straddles a batch)
    const int b  = rb >> 9;
    const int t  = threadIdx.x;
    const int w  = t >> 6, l = t & 63;     // wave w owns row rb+w

    __shared__ float qs[4 * 64];
    __shared__ float p[4 * 512];

    qs[t] = Q[rb * 64 + t];                // 256 = 4 rows x 64
    __syncthreads();

    // scores: thread t handles j = t and j = t+256, 4 q-rows per K read
#pragma unroll
    for (int half = 0; half < 2; ++half) {
        const int j = half * 256 + t;
        const f4* kr = (const f4*)(K + (size_t)(b * NN + j) * 64);
        float s0 = 0.f, s1 = 0.f, s2 = 0.f, s3 = 0.f;
#pragma unroll
        for (int u = 0; u < 16; ++u) {
            const f4 kv = kr[u];
            const f4 qa = ((const f4*)qs)[u];
            const f4 qb = ((const f4*)(qs + 64))[u];
            const f4 qc = ((const f4*)(qs + 128))[u];
            const f4 qd = ((const f4*)(qs + 192))[u];
            s0 += kv.x * qa.x + kv.y * qa.y + kv.z * qa.z + kv.w * qa.w;
            s1 += kv.x * qb.x + kv.y * qb.y + kv.z * qb.z + kv.w * qb.w;
            s2 += kv.x * qc.x + kv.y * qc.y + kv.z * qc.z + kv.w * qc.w;
            s3 += kv.x * qd.x + kv.y * qd.y + kv.z * qd.z + kv.w * qd.w;
        }
        p[0 * 512 + j] = s0 * 0.125f;
        p[1 * 512 + j] = s1 * 0.125f;
        p[2 * 512 + j] = s2 * 0.125f;
        p[3 * 512 + j] = s3 * 0.125f;
    }
    __syncthreads();

    // wave-local softmax: wave w, row rb+w, 8 values/lane
    float* prw = p + w * 512;
    float v[8];
#pragma unroll
    for (int z = 0; z < 8; ++z) v[z] = prw[l + z * 64];
    float mx = v[0];
#pragma unroll
    for (int z = 1; z < 8; ++z) mx = fmaxf(mx, v[z]);
#pragma unroll
    for (int o = 1; o < 64; o <<= 1) mx = fmaxf(mx, __shfl_xor(mx, o));
    float se = 0.f;
#pragma unroll
    for (int z = 0; z < 8; ++z) { v[z] = expf(v[z] - mx); se += v[z]; prw[l + z * 64] = v[z]; }
#pragma unroll
    for (int o = 1; o < 64; o <<= 1) se += __shfl_xor(se, o);
    const float inv = 1.f / se;
    __syncthreads();

    // PV: wave w, lane l = output dim; V rows shared across the 4 waves via L1
    const float* Vb = V + (size_t)b * NN * 64;
    float a0 = 0.f, a1 = 0.f, a2 = 0.f, a3 = 0.f;
    const f4* pw4 = (const f4*)prw;
    for (int j4 = 0; j4 < 128; ++j4) {
        const f4 pv = pw4[j4];               // wave-broadcast
        const int j = j4 * 4;
        a0 = fmaf(pv.x, Vb[(j + 0) * 64 + l], a0);
        a1 = fmaf(pv.y, Vb[(j + 1) * 64 + l], a1);
        a2 = fmaf(pv.z, Vb[(j + 2) * 64 + l], a2);
        a3 = fmaf(pv.w, Vb[(j + 3) * 64 + l], a3);
    }
    xhat[(size_t)(rb + w) * 64 + l] = ((a0 + a1) + (a2 + a3)) * inv;
}

// ---------------- fused affine maps of xhat: Qn, Vn, P, VnWke, VnWve, q0 ----------------
__global__ __launch_bounds__(256) void affine5_kernel(
    const float* __restrict__ xhat,
    const float* __restrict__ Wqn, const float* __restrict__ bqn,
    const float* __restrict__ Wvn, const float* __restrict__ bvn,
    const float* __restrict__ M_P, const float* __restrict__ c_P,
    const float* __restrict__ M_ke, const float* __restrict__ c_ke,
    const float* __restrict__ M_ve, const float* __restrict__ c_ve,
    const float* __restrict__ vq0, const float* __restrict__ s0p,
    float* __restrict__ Qn, float* __restrict__ Vn, float* __restrict__ P,
    float* __restrict__ VnWke, float* __restrict__ VnWve, float* __restrict__ q0)
{
    const int t = threadIdx.x;
    const int rb = blockIdx.x * 32;
    const int m = blockIdx.y;
    const float* W; const float* c; float* o;
    if (m == 0)      { W = Wqn;  c = bqn;  o = Qn; }
    else if (m == 1) { W = Wvn;  c = bvn;  o = Vn; }
    else if (m == 2) { W = M_P;  c = c_P;  o = P; }
    else if (m == 3) { W = M_ke; c = c_ke; o = VnWke; }
    else             { W = M_ve; c = c_ve; o = VnWve; }
    __shared__ float Ws[4096], xs[2048], cs[64], vq0s[64];
#pragma unroll
    for (int p = 0; p < 4; ++p) ((f4*)Ws)[p * 256 + t] = ((const f4*)W)[p * 256 + t];
    ((f4*)xs)[t]       = ((const f4*)(xhat + rb * 64))[t];
    ((f4*)xs)[t + 256] = ((const f4*)(xhat + rb * 64))[t + 256];
    if (t < 64) { cs[t] = c[t]; if (m == 0) vq0s[t] = vq0[t]; }
    __syncthreads();

    const int d = t & 63, g = t >> 6;
    float acc[8];
#pragma unroll
    for (int r = 0; r < 8; ++r) acc[r] = cs[d];
    for (int k4 = 0; k4 < 16; ++k4) {
        float w[4];
#pragma unroll
        for (int kk = 0; kk < 4; ++kk) w[kk] = Ws[(k4 * 4 + kk) * 64 + d];
#pragma unroll
        for (int r = 0; r < 8; ++r) {
            const f4 xv = ((const f4*)xs)[(g * 8 + r) * 16 + k4];
            acc[r] = fmaf(xv.x, w[0], fmaf(xv.y, w[1], fmaf(xv.z, w[2], fmaf(xv.w, w[3], acc[r]))));
        }
    }
#pragma unroll
    for (int r = 0; r < 8; ++r) o[(rb + g * 8 + r) * 64 + d] = acc[r];

    if (m == 0) {
        const int row = t >> 3, seg = t & 7;
        float part = 0.f;
#pragma unroll
        for (int kk = 0; kk < 8; ++kk)
            part = fmaf(xs[row * 64 + seg * 8 + kk], vq0s[seg * 8 + kk], part);
        part += __shfl_xor(part, 1);
        part += __shfl_xor(part, 2);
        part += __shfl_xor(part, 4);
        if (seg == 0) q0[rb + row] = part + s0p[0];
    }
}

// ---------- streaming edge pass with ONLINE edge-to-node reductions (R12 best form) ----------
__global__ __launch_bounds__(256, 4) void edge_kernel(
    const float* __restrict__ e, const float* __restrict__ P,
    const float* __restrict__ q0, const float* __restrict__ Vn,
    const float* __restrict__ Qn, const float* __restrict__ VnWke,
    const float* __restrict__ VnWve,
    float* __restrict__ e_new,
    float* __restrict__ Epart, float* __restrict__ Gpart, float* __restrict__ Wpart)
{
    const int blk = blockIdx.x;
    const int bi = blk >> 3;         // b*512 + i
    const int jc = blk & 7;          // 64-j chunk
    const int b  = bi >> 9;
    const int t  = threadIdx.x;
    const int r  = t >> 4;           // row slot 0..15
    const int k  = t & 15;           // float4 lane

    const f4* erow  = (const f4*)(e     + (size_t)bi * NN * 64);
    f4*       enrow = (f4*)      (e_new + (size_t)bi * NN * 64);
    const f4* Prow  = (const f4*)P     + (size_t)b * NN * 16;
    const f4* Vrow  = (const f4*)Vn    + (size_t)b * NN * 16;
    const f4* Krow  = (const f4*)VnWke + (size_t)b * NN * 16;
    const f4* Wvrow = (const f4*)VnWve + (size_t)b * NN * 16;
    const float* q0b = q0 + b * NN;

    const int j0 = jc * 64 + r;
    const int j1 = j0 + 16, j2 = j0 + 32, j3 = j0 + 48;

    const f4 ev0 = erow[j0 * 16 + k];
    const f4 ev1 = erow[j1 * 16 + k];
    const f4 ev2 = erow[j2 * 16 + k];
    const f4 ev3 = erow[j3 * 16 + k];

    const float q0i = q0[bi];
    const f4 pi4 = ((const f4*)P)[bi * 16 + k];
    const f4 vi4 = ((const f4*)Vn)[bi * 16 + k];
    const f4 qn4 = ((const f4*)Qn)[bi * 16 + k];
    const f4 wi4 = ((const f4*)VnWke)[bi * 16 + k];
    float uii = qn4.x * wi4.x + qn4.y * wi4.y + qn4.z * wi4.z + qn4.w * wi4.w;
    uii += __shfl_xor(uii, 1);
    uii += __shfl_xor(uii, 2);
    uii += __shfl_xor(uii, 4);
    uii += __shfl_xor(uii, 8);
    uii *= 0.125f;

    float Eacc = 0.f, Gacc = 0.f;
    f4 Wacc = {0.f, 0.f, 0.f, 0.f};

#define EDGE_ITER(EV, J)                                                        \
    {                                                                           \
        const f4 pj = Prow[(J) * 16 + k];                                       \
        const f4 wj = Krow[(J) * 16 + k];                                       \
        const f4 vj = Vrow[(J) * 16 + k];                                       \
        const f4 wv = Wvrow[(J) * 16 + k];                                      \
        const float qj = q0b[(J)];                                              \
        float s = EV.x * (pj.x - pi4.x) + EV.y * (pj.y - pi4.y)                 \
                + EV.z * (pj.z - pi4.z) + EV.w * (pj.w - pi4.w);                \
        float uu = qn4.x * wj.x + qn4.y * wj.y + qn4.z * wj.z + qn4.w * wj.w;   \
        s  += __shfl_xor(s, 1);  uu += __shfl_xor(uu, 1);                       \
        s  += __shfl_xor(s, 2);  uu += __shfl_xor(uu, 2);                       \
        s  += __shfl_xor(s, 4);  uu += __shfl_xor(uu, 4);                       \
        s  += __shfl_xor(s, 8);  uu += __shfl_xor(uu, 8);                       \
        const float ai = 1.f / (1.f + expf(-(s * 0.125f + qj - q0i)));          \
        f4 en;                                                                  \
        en.x = fmaf(ai, vj.x - vi4.x, vi4.x);                                   \
        en.y = fmaf(ai, vj.y - vi4.y, vi4.y);                                   \
        en.z = fmaf(ai, vj.z - vi4.z, vi4.z);                                   \
        en.w = fmaf(ai, vj.w - vi4.w, vi4.w);                                   \
        __builtin_nontemporal_store(en, enrow + (J) * 16 + k);                  \
        const float ex  = expf(ai * (uu * 0.125f - uii));                       \
        const float aex = ai * ex;                                              \
        Eacc += ex;                                                             \
        Gacc += aex;                                                            \
        Wacc.x = fmaf(aex, wv.x, Wacc.x);                                       \
        Wacc.y = fmaf(aex, wv.y, Wacc.y);                                       \
        Wacc.z = fmaf(aex, wv.z, Wacc.z);                                       \
        Wacc.w = fmaf(aex, wv.w, Wacc.w);                                       \
    }

    EDGE_ITER(ev0, j0)
    EDGE_ITER(ev1, j1)
    EDGE_ITER(ev2, j2)
    EDGE_ITER(ev3, j3)
#undef EDGE_ITER

    Eacc += __shfl_xor(Eacc, 16);  Eacc += __shfl_xor(Eacc, 32);
    Gacc += __shfl_xor(Gacc, 16);  Gacc += __shfl_xor(Gacc, 32);
    Wacc.x += __shfl_xor(Wacc.x, 16);  Wacc.x += __shfl_xor(Wacc.x, 32);
    Wacc.y += __shfl_xor(Wacc.y, 16);  Wacc.y += __shfl_xor(Wacc.y, 32);
    Wacc.z += __shfl_xor(Wacc.z, 16);  Wacc.z += __shfl_xor(Wacc.z, 32);
    Wacc.w += __shfl_xor(Wacc.w, 16);  Wacc.w += __shfl_xor(Wacc.w, 32);

    __shared__ float Wred[4][65];
    __shared__ float EG[8];
    const int l = t & 63, w = t >> 6;
    if (l < 16) {
        Wred[w][l * 4 + 0] = Wacc.x;
        Wred[w][l * 4 + 1] = Wacc.y;
        Wred[w][l * 4 + 2] = Wacc.z;
        Wred[w][l * 4 + 3] = Wacc.w;
        if (l == 0) { EG[w] = Eacc; EG[4 + w] = Gacc; }
    }
    __syncthreads();
    if (t < 64) {
        const float Wsum = Wred[0][t] + Wred[1][t] + Wred[2][t] + Wred[3][t];
        Wpart[((size_t)jc * RR + bi) * 64 + t] = Wsum;
        if (t == 0) {
            Epart[jc * RR + bi] = EG[0] + EG[1] + EG[2] + EG[3];
            Gpart[jc * RR + bi] = EG[4] + EG[5] + EG[6] + EG[7];
        }
    }
}

// ---------- final: combine 8 partials, 4 rows/block -> x_new ----------
__global__ __launch_bounds__(256) void final4_kernel(
    const float* __restrict__ Epart, const float* __restrict__ Gpart,
    const float* __restrict__ Wpart, const float* __restrict__ VnWve,
    const float* __restrict__ bve, float* __restrict__ x_new)
{
    const int bi = blockIdx.x * 4 + (threadIdx.x >> 6);
    const int t = threadIdx.x & 63;
    float Wsum = 0.f;
#pragma unroll
    for (int jc = 0; jc < 8; ++jc)
        Wsum += Wpart[((size_t)jc * RR + bi) * 64 + t];
    float E = 0.f, G = 0.f;
#pragma unroll
    for (int jc = 0; jc < 8; ++jc) {
        E += Epart[jc * RR + bi];
        G += Gpart[jc * RR + bi];
    }
    const float inv = 1.f / E;
    x_new[(size_t)bi * 64 + t] = bve[t] + VnWve[(size_t)bi * 64 + t] * (1.f - G * inv)
                               + Wsum * inv;
}

extern "C" void kernel_launch(void* const* d_in, const int* in_sizes, int n_in,
                              void* d_out, int out_size, void* d_ws, size_t ws_size,
                              hipStream_t stream) {
    const float* x   = (const float*)d_in[0];
    const float* e   = (const float*)d_in[1];
    const float* Wq1 = (const float*)d_in[2];  const float* bq1 = (const float*)d_in[3];
    const float* Wk1 = (const float*)d_in[4];  const float* bk1 = (const float*)d_in[5];
    const float* Wv1 = (const float*)d_in[6];  const float* bv1 = (const float*)d_in[7];
    const float* Wqe = (const float*)d_in[8];  const float* bqe = (const float*)d_in[9];
    const float* Wkn = (const float*)d_in[10]; const float* bkn = (const float*)d_in[11];
    const float* Wvn = (const float*)d_in[12]; const float* bvn = (const float*)d_in[13];
    const float* Wqn = (const float*)d_in[14]; const float* bqn = (const float*)d_in[15];
    const float* Wke = (const float*)d_in[16]; /* bke cancels in softmax */
    const float* Wve = (const float*)d_in[18]; const float* bve = (const float*)d_in[19];

    float* out = (float*)d_out;
    float* x_new = out;                 // (2,512,64)
    float* e_new = out + 2 * NN * 64;   // (2,512,512,64)

    float* ws = (float*)d_ws;
    float* Q     = ws;                  // RR*64 each
    float* K     = Q + RR * 64;
    float* V     = K + RR * 64;
    float* xhat  = V + RR * 64;
    float* Qn    = xhat + RR * 64;
    float* Vn    = Qn + RR * 64;
    float* P     = Vn + RR * 64;
    float* VnWke = P + RR * 64;
    float* VnWve = VnWke + RR * 64;
    float* q0    = VnWve + RR * 64;     // RR
    float* M_P   = q0 + RR;             // 4096 each
    float* M_ke  = M_P + 4096;
    float* M_ve  = M_ke + 4096;
    float* c_P   = M_ve + 4096;         // 64 each
    float* c_ke  = c_P + 64;
    float* c_ve  = c_ke + 64;
    float* vq0   = c_ve + 64;
    float* s0    = vq0 + 64;            // 64 (pad)
    float* Epart = s0 + 64;             // 8*RR
    float* Gpart = Epart + 8 * RR;      // 8*RR
    float* Wpart = Gpart + 8 * RR;      // 8*RR*64

    prep_kernel<<<35, 256, 0, stream>>>(x, Wq1, bq1, Wk1, bk1, Wv1, bv1,
                                        Wkn, bkn, Wvn, bvn, Wqe, bqe, Wke, Wve,
                                        Q, K, V,
                                        M_P, c_P, M_ke, c_ke, M_ve, c_ve, vq0, s0);
    selfattn4_kernel<<<RR / 4, 256, 0, stream>>>(Q, K, V, xhat);
    affine5_kernel<<<dim3(32, 5), 256, 0, stream>>>(xhat, Wqn, bqn, Wvn, bvn,
                                                    M_P, c_P, M_ke, c_ke, M_ve, c_ve,
                                                    vq0, s0,
                                                    Qn, Vn, P, VnWke, VnWve, q0);
    edge_kernel<<<RR * 8, 256, 0, stream>>>(e, P, q0, Vn, Qn, VnWke, VnWve,
                                            e_new, Epart, Gpart, Wpart);
    final4_kernel<<<RR / 4, 256, 0, stream>>>(Epart, Gpart, Wpart, VnWve, bve, x_new);
}